// Round 3
// baseline (1769.186 us; speedup 1.0000x reference)
//
#include <hip/hip_runtime.h>

#define BB 16384
#define GG 8192
#define DD 256
#define CS 32          // candidate slots per row
#define EPS 0.012f     // > 2B, B = 2^-8 bf16-RNE Cauchy-Schwarz bound on cosine scale

typedef __attribute__((ext_vector_type(8))) short bf16x8;
typedef __attribute__((ext_vector_type(4))) float f32x4;
typedef unsigned int u32;
typedef unsigned short u16;

__device__ __forceinline__ u32 enc_f32(float v) {
    u32 u = __float_as_uint(v);
    return (u & 0x80000000u) ? ~u : (u | 0x80000000u);
}
__device__ __forceinline__ float dec_f32(u32 e) {
    u32 u = (e & 0x80000000u) ? (e ^ 0x80000000u) : ~u - 0u;  // placeholder, fixed below
    return __uint_as_float(u);
}
// (correct decoder)
__device__ __forceinline__ float dec_f32_ok(u32 e) {
    u32 u = (e & 0x80000000u) ? (e ^ 0x80000000u) : ~e;
    return __uint_as_float(u);
}

__device__ __forceinline__ void async_copy16(const void* g, u16* lds) {
    __builtin_amdgcn_global_load_lds(
        (const __attribute__((address_space(1))) void*)g,
        (__attribute__((address_space(3))) void*)lds, 16, 0, 0);
}

// ---------------- prep: fp32 -> bf16 (RNE) + inverse norms (4 rows/block) ----
__global__ __launch_bounds__(256)
void prep_kernel(const float* __restrict__ src, u16* __restrict__ dstb,
                 float* __restrict__ invn) {
    int wid = threadIdx.x >> 6, lane = threadIdx.x & 63;
    size_t r = (size_t)blockIdx.x * 4 + wid;
    float4 v = ((const float4*)(src + r * DD))[lane];
    float vv[4] = {v.x, v.y, v.z, v.w};
    u16 b[4];
    float ss = 0.f;
    #pragma unroll
    for (int k = 0; k < 4; ++k) {
        u32 u = __float_as_uint(vv[k]);
        b[k] = (u16)((u + 0x7fffu + ((u >> 16) & 1u)) >> 16);   // RNE bf16
        ss = fmaf(vv[k], vv[k], ss);
    }
    ushort4 pk; pk.x = b[0]; pk.y = b[1]; pk.z = b[2]; pk.w = b[3];
    ((ushort4*)(dstb + r * DD))[lane] = pk;
    #pragma unroll
    for (int off = 1; off < 64; off <<= 1) ss += __shfl_xor(ss, off);
    if (lane == 0) invn[r] = 1.0f / fmaxf(sqrtf(ss), 1e-12f);
}

// ---------------- GEMM + strip-max + candidate collection ----------------
// 128x128 tile, BK=32, 4 waves (2x2), double-buffered LDS, pair-line swizzle.
__global__ __launch_bounds__(256)
void gemm_kernel(const u16* __restrict__ xb, const u16* __restrict__ gb,
                 const float* __restrict__ invx, const float* __restrict__ invg,
                 u32* __restrict__ amax, u32* __restrict__ ccnt,
                 u16* __restrict__ cand) {
    __shared__ u16 lds[2 * 8192];   // [buf][A 4096 | B 4096] shorts = 32 KB

    const int tid  = threadIdx.x;
    const int lane = tid & 63;
    const int w    = tid >> 6;
    const int wr   = w >> 1, wc = w & 1;
    const int m0   = blockIdx.x * 128;
    const int g0   = blockIdx.y * 128;

    // staging source permutation: LDS stays linear; lane l fetches the global
    // (row,slot) that belongs at swizzled position (line=l>>3, slot8'=l&7),
    // where stored slot8 = slot8' ^ (line&7).
    const int s8g    = (lane & 7) ^ (lane >> 3);
    const int rowadd = 2 * (lane >> 3) + (s8g >> 2);
    const int koff   = (s8g & 3) * 8;

    f32x4 acc[4][4];
    #pragma unroll
    for (int i = 0; i < 4; ++i)
        #pragma unroll
        for (int j = 0; j < 4; ++j) acc[i][j] = (f32x4){0.f, 0.f, 0.f, 0.f};

    auto stage = [&](int buf, int k0) {
        #pragma unroll
        for (int q = 0; q < 2; ++q) {
            int R0 = w * 32 + q * 16;    // 16-row chunk (8 pair-lines, 1024 B)
            async_copy16(xb + (size_t)(m0 + R0 + rowadd) * DD + k0 + koff,
                         &lds[buf * 8192 + R0 * 32]);
            async_copy16(gb + (size_t)(g0 + R0 + rowadd) * DD + k0 + koff,
                         &lds[buf * 8192 + 4096 + R0 * 32]);
        }
    };

    stage(0, 0);
    __syncthreads();                 // vmcnt(0) drain + barrier

    const int fr  = lane & 15;
    const int sl  = lane >> 4;
    const int s8s = ((fr & 1) * 4 + sl) ^ (fr >> 1);  // swizzled slot8 for reads

    int cur = 0;
    for (int t = 0; t < 8; ++t) {
        if (t < 7) stage(cur ^ 1, (t + 1) * 32);      // prefetch in flight during MFMA
        bf16x8 af[4], bf[4];
        #pragma unroll
        for (int i = 0; i < 4; ++i) {
            int lineA = wr * 32 + i * 8 + (fr >> 1);  // (row>>1), row = wr*64+i*16+fr
            af[i] = *(const bf16x8*)&lds[cur * 8192 + lineA * 64 + s8s * 8];
            int lineB = wc * 32 + i * 8 + (fr >> 1);
            bf[i] = *(const bf16x8*)&lds[cur * 8192 + 4096 + lineB * 64 + s8s * 8];
        }
        #pragma unroll
        for (int i = 0; i < 4; ++i)
            #pragma unroll
            for (int j = 0; j < 4; ++j)
                acc[i][j] = __builtin_amdgcn_mfma_f32_16x16x32_bf16(
                    af[i], bf[j], acc[i][j], 0, 0, 0);
        __syncthreads();             // drains stage vmcnt + frag lgkm, then barrier
        cur ^= 1;
    }

    // epilogue: cosine scale, strip max, running-global filter, collect candidates
    const int fq = lane >> 4;
    float ivg[4];
    #pragma unroll
    for (int j = 0; j < 4; ++j) ivg[j] = invg[g0 + wc * 64 + j * 16 + fr];

    #pragma unroll
    for (int i = 0; i < 4; ++i) {
        #pragma unroll
        for (int r = 0; r < 4; ++r) {
            int row = m0 + wr * 64 + i * 16 + fq * 4 + r;
            float ivx = invx[row];
            float v[4], m = -3.0e38f;
            #pragma unroll
            for (int j = 0; j < 4; ++j) {
                v[j] = acc[i][j][r] * ivg[j] * ivx;
                m = fmaxf(m, v[j]);
            }
            #pragma unroll
            for (int off = 1; off < 16; off <<= 1)
                m = fmaxf(m, __shfl_xor(m, off));     // strip max (128 cols)
            u32 old = 0;
            if (fr == 0) old = atomicMax(&amax[row], enc_f32(m));
            float gprev = dec_f32_ok(old);            // NaN if amax was 0-init
            float curmax = fmaxf(m, __shfl(gprev, lane & 48));
            float thr = curmax - EPS;
            #pragma unroll
            for (int j = 0; j < 4; ++j) {
                if (v[j] >= thr) {
                    u32 c = atomicAdd(&ccnt[row], 1u);
                    if (c < CS) cand[(size_t)row * CS + c] =
                        (u16)(g0 + wc * 64 + j * 16 + fr);
                }
            }
        }
    }
}

// ---------------- resolve: exact fp32 re-eval of candidates + fused scatter ----
__global__ __launch_bounds__(256)
void resolve_kernel(const float* __restrict__ x, const float* __restrict__ gf,
                    const float* __restrict__ invg, const u32* __restrict__ ccnt,
                    const u16* __restrict__ cand,
                    float* __restrict__ sums, float* __restrict__ counts) {
    __shared__ float xs[4][DD];
    int wid = threadIdx.x >> 6, lane = threadIdx.x & 63;
    int row = blockIdx.x * 4 + wid;
    float4 xv = ((const float4*)(x + (size_t)row * DD))[lane];
    ((float4*)xs[wid])[lane] = xv;   // wave-local staging (same-wave consume)

    u32 cnt = ccnt[row];
    float best = -3.0e38f; int bcol = GG - 1;
    if (cnt >= 1 && cnt <= CS) {
        for (u32 c = 0; c < cnt; ++c) {
            int col = cand[(size_t)row * CS + c];
            float4 gv = ((const float4*)(gf + (size_t)col * DD))[lane];
            float p = fmaf(xv.x, gv.x, fmaf(xv.y, gv.y,
                      fmaf(xv.z, gv.z, xv.w * gv.w)));
            #pragma unroll
            for (int off = 1; off < 64; off <<= 1) p += __shfl_xor(p, off);
            float v = p * invg[col];
            if (v > best || (v == best && col < bcol)) { best = v; bcol = col; }
        }
    } else {
        // overflow (or impossible empty): exact scan over all groups
        for (int col = lane; col < GG; col += 64) {
            const float4* gr = (const float4*)(gf + (size_t)col * DD);
            float s = 0.f;
            #pragma unroll 8
            for (int d = 0; d < 64; ++d) {
                float4 g4 = gr[d];
                s = fmaf(xs[wid][d * 4 + 0], g4.x, s);
                s = fmaf(xs[wid][d * 4 + 1], g4.y, s);
                s = fmaf(xs[wid][d * 4 + 2], g4.z, s);
                s = fmaf(xs[wid][d * 4 + 3], g4.w, s);
            }
            float v = s * invg[col];
            if (v > best || (v == best && col < bcol)) { best = v; bcol = col; }
        }
        #pragma unroll
        for (int off = 1; off < 64; off <<= 1) {
            float ov = __shfl_xor(best, off);
            int   oc = __shfl_xor(bcol, off);
            if (ov > best || (ov == best && oc < bcol)) { best = ov; bcol = oc; }
        }
    }
    // fused scatter-mean accumulation
    if (lane == 0) atomicAdd(&counts[bcol], 1.0f);
    float* sp = sums + (size_t)bcol * DD + lane * 4;
    atomicAdd(sp + 0, xv.x); atomicAdd(sp + 1, xv.y);
    atomicAdd(sp + 2, xv.z); atomicAdd(sp + 3, xv.w);
}

// ---------------- EMA finalize ----------------
__global__ __launch_bounds__(256)
void final_kernel(const float* __restrict__ gf, const float* __restrict__ sums,
                  const float* __restrict__ counts, float* __restrict__ out) {
    int i = blockIdx.x * 256 + threadIdx.x;
    int g = i >> 8;
    out[i] = 0.99f * gf[i] + 0.01f * (sums[i] / fmaxf(counts[g], 1.0f));
}

extern "C" void kernel_launch(void* const* d_in, const int* in_sizes, int n_in,
                              void* d_out, int out_size, void* d_ws, size_t ws_size,
                              hipStream_t stream) {
    const float* x  = (const float*)d_in[0];   // [16384, 256]
    const float* gf = (const float*)d_in[1];   // [8192, 256]
    float* out = (float*)d_out;

    char* ws = (char*)d_ws;
    u16*   xb     = (u16*)ws;                       // 8 MB (sums aliases later)
    u16*   gb     = (u16*)(ws + 8388608);           // 4 MB
    float* invx   = (float*)(ws + 12582912);        // 64 KB
    float* invg   = (float*)(ws + 12648448);        // 32 KB
    u32*   amax   = (u32*)  (ws + 12681216);        // 64 KB
    u32*   ccnt   = (u32*)  (ws + 12746752);        // 64 KB
    float* counts = (float*)(ws + 12812288);        // 32 KB
    u16*   cand   = (u16*)  (ws + 12845056);        // 1 MB
    float* sums   = (float*)ws;                     // aliases xb (dead after gemm)

    // zero amax+ccnt+counts (contiguous 160 KB)
    hipMemsetAsync(amax, 0, 160 * 1024, stream);

    prep_kernel<<<BB / 4, 256, 0, stream>>>(x,  xb, invx);
    prep_kernel<<<GG / 4, 256, 0, stream>>>(gf, gb, invg);

    gemm_kernel<<<dim3(BB / 128, GG / 128), 256, 0, stream>>>(
        xb, gb, invx, invg, amax, ccnt, cand);

    hipMemsetAsync(sums, 0, 8388608, stream);       // xb dead; reuse as sums

    resolve_kernel<<<BB / 4, 256, 0, stream>>>(x, gf, invg, ccnt, cand, sums, counts);
    final_kernel<<<GG * DD / 256, 256, 0, stream>>>(gf, sums, counts, out);
}

// Round 4
// 1057.573 us; speedup vs baseline: 1.6729x; 1.6729x over previous
//
#include <hip/hip_runtime.h>

#define BB 16384
#define GG 8192
#define DD 256
#define CS 40          // candidate slots per row (overflow -> exact fallback)
#define EPS 0.012f     // > 2B, B = 2^-8 bf16-RNE Cauchy-Schwarz bound on cosine scale
#define GSPLIT 8
#define GCH (GG / GSPLIT)    // 1024 groups per chunk
#define NSTEP (GCH / 128 * 8) // 8 g-tiles x 8 k-steps = 64

typedef __attribute__((ext_vector_type(8))) short bf16x8;
typedef __attribute__((ext_vector_type(4))) float f32x4;
typedef unsigned int u32;
typedef unsigned short u16;

__device__ __forceinline__ u32 enc_f32(float v) {
    u32 u = __float_as_uint(v);
    return (u & 0x80000000u) ? ~u : (u | 0x80000000u);
}
__device__ __forceinline__ float dec_f32(u32 e) {
    u32 u = (e & 0x80000000u) ? (e ^ 0x80000000u) : ~e;
    return __uint_as_float(u);   // dec(0) = NaN; fmaxf(x, NaN) = x
}

__device__ __forceinline__ void async_copy16(const void* g, u16* lds) {
    __builtin_amdgcn_global_load_lds(
        (const __attribute__((address_space(1))) void*)g,
        (__attribute__((address_space(3))) void*)lds, 16, 0, 0);
}

// ---------------- prep: fp32 -> bf16 (RNE) + inverse norms (4 rows/block) ----
__global__ __launch_bounds__(256)
void prep_kernel(const float* __restrict__ src, u16* __restrict__ dstb,
                 float* __restrict__ invn) {
    int wid = threadIdx.x >> 6, lane = threadIdx.x & 63;
    size_t r = (size_t)blockIdx.x * 4 + wid;
    float4 v = ((const float4*)(src + r * DD))[lane];
    float vv[4] = {v.x, v.y, v.z, v.w};
    u16 b[4];
    float ss = 0.f;
    #pragma unroll
    for (int k = 0; k < 4; ++k) {
        u32 u = __float_as_uint(vv[k]);
        b[k] = (u16)((u + 0x7fffu + ((u >> 16) & 1u)) >> 16);   // RNE bf16
        ss = fmaf(vv[k], vv[k], ss);
    }
    ushort4 pk; pk.x = b[0]; pk.y = b[1]; pk.z = b[2]; pk.w = b[3];
    ((ushort4*)(dstb + r * DD))[lane] = pk;
    #pragma unroll
    for (int off = 1; off < 64; off <<= 1) ss += __shfl_xor(ss, off);
    if (lane == 0) invn[r] = 1.0f / fmaxf(sqrtf(ss), 1e-12f);
}

// ---------------- GEMM: loop over G-chunk, monotone running max, collect ----
// grid (BB/128, GSPLIT). 128x128 tiles, BK=32, 4 waves (2x2), dbuf + swizzle.
__global__ __launch_bounds__(256, 2)
void gemm_kernel(const u16* __restrict__ xb, const u16* __restrict__ gb,
                 const float* __restrict__ invx, const float* __restrict__ invg,
                 u32* __restrict__ amax, u32* __restrict__ ccnt,
                 u16* __restrict__ cand) {
    __shared__ u16 lds[2 * 8192];   // [buf][A 4096 | B 4096] shorts = 32 KB

    const int tid   = threadIdx.x;
    const int lane  = tid & 63;
    const int w     = tid >> 6;
    const int wr    = w >> 1, wc = w & 1;
    const int m0    = blockIdx.x * 128;
    const int cbase = blockIdx.y * GCH;

    // staging source permutation (LDS linear; stored slot8 = global_slot8 ^ line)
    const int s8g    = (lane & 7) ^ (lane >> 3);
    const int rowadd = 2 * (lane >> 3) + (s8g >> 2);
    const int koff   = (s8g & 3) * 8;

    const int fr = lane & 15;
    const int fq = lane >> 4;
    const int s8s = ((fr & 1) * 4 + (lane >> 4)) ^ (fr >> 1);  // swizzled read slot
    // NOTE: for frag reads the k-slice is sl = lane>>4 == fq.

    // preload per-row inv-norms for my 16 (i,r) rows
    float ivx[16];
    #pragma unroll
    for (int i = 0; i < 4; ++i)
        #pragma unroll
        for (int r = 0; r < 4; ++r)
            ivx[i * 4 + r] = invx[m0 + wr * 64 + i * 16 + fq * 4 + r];

    float running[16];
    #pragma unroll
    for (int i = 0; i < 16; ++i) running[i] = -3.0e38f;

    f32x4 acc[4][4];
    #pragma unroll
    for (int i = 0; i < 4; ++i)
        #pragma unroll
        for (int j = 0; j < 4; ++j) acc[i][j] = (f32x4){0.f, 0.f, 0.f, 0.f};

    auto stage = [&](int buf, int gt, int k0) {
        #pragma unroll
        for (int q = 0; q < 2; ++q) {
            int R0 = w * 32 + q * 16;    // 16-row chunk = 8 swizzle lines
            async_copy16(xb + (size_t)(m0 + R0 + rowadd) * DD + k0 + koff,
                         &lds[buf * 8192 + R0 * 32]);
            async_copy16(gb + (size_t)(cbase + gt * 128 + R0 + rowadd) * DD + k0 + koff,
                         &lds[buf * 8192 + 4096 + R0 * 32]);
        }
    };

    stage(0, 0, 0);
    __syncthreads();

    int cur = 0;
    for (int s = 0; s < NSTEP; ++s) {
        const int gt = s >> 3;
        if (s < NSTEP - 1) stage(cur ^ 1, (s + 1) >> 3, ((s + 1) & 7) * 32);

        bf16x8 af[4], bf[4];
        #pragma unroll
        for (int i = 0; i < 4; ++i) {
            int lineA = wr * 32 + i * 8 + (fr >> 1);
            af[i] = *(const bf16x8*)&lds[cur * 8192 + lineA * 64 + s8s * 8];
            int lineB = wc * 32 + i * 8 + (fr >> 1);
            bf[i] = *(const bf16x8*)&lds[cur * 8192 + 4096 + lineB * 64 + s8s * 8];
        }
        #pragma unroll
        for (int i = 0; i < 4; ++i)
            #pragma unroll
            for (int j = 0; j < 4; ++j)
                acc[i][j] = __builtin_amdgcn_mfma_f32_16x16x32_bf16(
                    af[i], bf[j], acc[i][j], 0, 0, 0);

        if ((s & 7) == 7) {
            // ---- per-g-tile epilogue: monotone filter + candidate collect ----
            const int g0 = cbase + gt * 128;
            float ivg4[4];
            #pragma unroll
            for (int j = 0; j < 4; ++j) ivg4[j] = invg[g0 + wc * 64 + j * 16 + fr];
            #pragma unroll
            for (int i = 0; i < 4; ++i) {
                #pragma unroll
                for (int r = 0; r < 4; ++r) {
                    float u0 = acc[i][0][r] * ivg4[0];
                    float u1 = acc[i][1][r] * ivg4[1];
                    float u2 = acc[i][2][r] * ivg4[2];
                    float u3 = acc[i][3][r] * ivg4[3];
                    float sm = fmaxf(fmaxf(u0, u1), fmaxf(u2, u3));
                    #pragma unroll
                    for (int off = 1; off < 16; off <<= 1)
                        sm = fmaxf(sm, __shfl_xor(sm, off));   // strip max over fr
                    const int row = m0 + wr * 64 + i * 16 + fq * 4 + r;
                    const float ivxr = ivx[i * 4 + r];
                    float mcos = fmaxf(running[i * 4 + r], sm * ivxr);
                    u32 old = 0;
                    if (fr == 0) old = atomicMax(&amax[row], enc_f32(mcos));
                    old = __shfl(old, lane & 48);   // broadcast within fq group
                    float gmax = fmaxf(mcos, dec_f32(old));
                    running[i * 4 + r] = gmax;
                    float thr = gmax - EPS;
                    #pragma unroll
                    for (int j = 0; j < 4; ++j) {
                        float v = (j == 0 ? u0 : j == 1 ? u1 : j == 2 ? u2 : u3) * ivxr;
                        if (v >= thr) {
                            u32 c = atomicAdd(&ccnt[row], 1u);
                            if (c < CS) cand[(size_t)row * CS + c] =
                                (u16)(g0 + wc * 64 + j * 16 + fr);
                        }
                    }
                }
            }
            #pragma unroll
            for (int i = 0; i < 4; ++i)
                #pragma unroll
                for (int j = 0; j < 4; ++j) acc[i][j] = (f32x4){0.f, 0.f, 0.f, 0.f};
        }
        __syncthreads();
        cur ^= 1;
    }
}

// ---------------- resolve: exact fp32 re-eval of candidates + fused scatter ----
__global__ __launch_bounds__(256)
void resolve_kernel(const float* __restrict__ x, const float* __restrict__ gf,
                    const float* __restrict__ invg, const u32* __restrict__ ccnt,
                    const u16* __restrict__ cand,
                    float* __restrict__ sums, float* __restrict__ counts) {
    __shared__ float xs[4][DD];
    int wid = threadIdx.x >> 6, lane = threadIdx.x & 63;
    int row = blockIdx.x * 4 + wid;
    float4 xv = ((const float4*)(x + (size_t)row * DD))[lane];
    ((float4*)xs[wid])[lane] = xv;   // wave-local staging (same-wave consume)

    u32 cnt = ccnt[row];
    float best = -3.0e38f; int bcol = GG - 1;
    if (cnt >= 1 && cnt <= CS) {
        for (u32 c = 0; c < cnt; ++c) {
            int col = cand[(size_t)row * CS + c];
            float4 gv = ((const float4*)(gf + (size_t)col * DD))[lane];
            float p = fmaf(xv.x, gv.x, fmaf(xv.y, gv.y,
                      fmaf(xv.z, gv.z, xv.w * gv.w)));
            #pragma unroll
            for (int off = 1; off < 64; off <<= 1) p += __shfl_xor(p, off);
            float v = p * invg[col];
            if (v > best || (v == best && col < bcol)) { best = v; bcol = col; }
        }
    } else {
        // overflow fallback: exact scan over all groups
        for (int col = lane; col < GG; col += 64) {
            const float4* gr = (const float4*)(gf + (size_t)col * DD);
            float s = 0.f;
            #pragma unroll 8
            for (int d = 0; d < 64; ++d) {
                float4 g4 = gr[d];
                s = fmaf(xs[wid][d * 4 + 0], g4.x, s);
                s = fmaf(xs[wid][d * 4 + 1], g4.y, s);
                s = fmaf(xs[wid][d * 4 + 2], g4.z, s);
                s = fmaf(xs[wid][d * 4 + 3], g4.w, s);
            }
            float v = s * invg[col];
            if (v > best || (v == best && col < bcol)) { best = v; bcol = col; }
        }
        #pragma unroll
        for (int off = 1; off < 64; off <<= 1) {
            float ov = __shfl_xor(best, off);
            int   oc = __shfl_xor(bcol, off);
            if (ov > best || (ov == best && oc < bcol)) { best = ov; bcol = oc; }
        }
    }
    // fused scatter-mean accumulation
    if (lane == 0) atomicAdd(&counts[bcol], 1.0f);
    float* sp = sums + (size_t)bcol * DD + lane * 4;
    atomicAdd(sp + 0, xv.x); atomicAdd(sp + 1, xv.y);
    atomicAdd(sp + 2, xv.z); atomicAdd(sp + 3, xv.w);
}

// ---------------- EMA finalize ----------------
__global__ __launch_bounds__(256)
void final_kernel(const float* __restrict__ gf, const float* __restrict__ sums,
                  const float* __restrict__ counts, float* __restrict__ out) {
    int i = blockIdx.x * 256 + threadIdx.x;
    int g = i >> 8;
    out[i] = 0.99f * gf[i] + 0.01f * (sums[i] / fmaxf(counts[g], 1.0f));
}

extern "C" void kernel_launch(void* const* d_in, const int* in_sizes, int n_in,
                              void* d_out, int out_size, void* d_ws, size_t ws_size,
                              hipStream_t stream) {
    const float* x  = (const float*)d_in[0];   // [16384, 256]
    const float* gf = (const float*)d_in[1];   // [8192, 256]
    float* out = (float*)d_out;

    char* ws = (char*)d_ws;
    u16*   xb     = (u16*)ws;                       // 8 MB (sums aliases later)
    u16*   gb     = (u16*)(ws + 8388608);           // 4 MB
    float* invx   = (float*)(ws + 12582912);        // 64 KB
    float* invg   = (float*)(ws + 12648448);        // 32 KB
    u32*   amax   = (u32*)  (ws + 12681216);        // 64 KB
    u32*   ccnt   = (u32*)  (ws + 12746752);        // 64 KB
    float* counts = (float*)(ws + 12812288);        // 32 KB
    u16*   cand   = (u16*)  (ws + 12845056);        // 1.25 MB (16384*40*2)
    float* sums   = (float*)ws;                     // aliases xb (dead after gemm)

    // zero amax+ccnt+counts (contiguous 160 KB)
    hipMemsetAsync(amax, 0, 160 * 1024, stream);

    prep_kernel<<<BB / 4, 256, 0, stream>>>(x,  xb, invx);
    prep_kernel<<<GG / 4, 256, 0, stream>>>(gf, gb, invg);

    gemm_kernel<<<dim3(BB / 128, GSPLIT), 256, 0, stream>>>(
        xb, gb, invx, invg, amax, ccnt, cand);

    hipMemsetAsync(sums, 0, 8388608, stream);       // xb dead; reuse as sums

    resolve_kernel<<<BB / 4, 256, 0, stream>>>(x, gf, invg, ccnt, cand, sums, counts);
    final_kernel<<<GG * DD / 256, 256, 0, stream>>>(gf, sums, counts, out);
}

// Round 5
// 448.417 us; speedup vs baseline: 3.9454x; 2.3585x over previous
//
#include <hip/hip_runtime.h>

#define BB 16384
#define GG 8192
#define DD 256
#define EPS   0.012f   // collection margin (bf16 dot err ~3e-4 RMS; ~30 sigma)
#define EPS_R 0.008f   // resolve re-filter margin vs final approx max (~25 sigma)
#define GSPLIT 8
#define GCH (GG / GSPLIT)     // 1024 groups per chunk
#define NSTEP (GCH / 128 * 8) // 8 g-tiles x 8 k-steps = 64

typedef __attribute__((ext_vector_type(8))) short bf16x8;
typedef __attribute__((ext_vector_type(4))) float f32x4;
typedef unsigned int u32;
typedef unsigned short u16;
typedef unsigned long long u64;

__device__ __forceinline__ u32 enc_f32(float v) {
    u32 u = __float_as_uint(v);
    return (u & 0x80000000u) ? ~u : (u | 0x80000000u);
}
__device__ __forceinline__ float dec_f32(u32 e) {
    u32 u = (e & 0x80000000u) ? (e ^ 0x80000000u) : ~e;
    return __uint_as_float(u);   // dec(0) = NaN; fmaxf(x, NaN) = x
}

__device__ __forceinline__ void async_copy16(const void* g, u16* lds) {
    __builtin_amdgcn_global_load_lds(
        (const __attribute__((address_space(1))) void*)g,
        (__attribute__((address_space(3))) void*)lds, 16, 0, 0);
}

// ---------------- prep: fp32 -> bf16 (RNE) + inverse norms (4 rows/block) ----
__global__ __launch_bounds__(256)
void prep_kernel(const float* __restrict__ src, u16* __restrict__ dstb,
                 float* __restrict__ invn) {
    int wid = threadIdx.x >> 6, lane = threadIdx.x & 63;
    size_t r = (size_t)blockIdx.x * 4 + wid;
    float4 v = ((const float4*)(src + r * DD))[lane];
    float vv[4] = {v.x, v.y, v.z, v.w};
    u16 b[4];
    float ss = 0.f;
    #pragma unroll
    for (int k = 0; k < 4; ++k) {
        u32 u = __float_as_uint(vv[k]);
        b[k] = (u16)((u + 0x7fffu + ((u >> 16) & 1u)) >> 16);   // RNE bf16
        ss = fmaf(vv[k], vv[k], ss);
    }
    ushort4 pk; pk.x = b[0]; pk.y = b[1]; pk.z = b[2]; pk.w = b[3];
    ((ushort4*)(dstb + r * DD))[lane] = pk;
    #pragma unroll
    for (int off = 1; off < 64; off <<= 1) ss += __shfl_xor(ss, off);
    if (lane == 0) invn[r] = 1.0f / fmaxf(sqrtf(ss), 1e-12f);
}

// ---------------- GEMM: loop over G-chunk, monotone running max, collect ----
// grid (BB/128, GSPLIT). 128x128 tiles, BK=32, 4 waves (2x2), dbuf + swizzle.
__global__ __launch_bounds__(256, 2)
void gemm_kernel(const u16* __restrict__ xb, const u16* __restrict__ gb,
                 const float* __restrict__ invx, const float* __restrict__ invg,
                 u32* __restrict__ amax, u32* __restrict__ ccnt,
                 u32* __restrict__ cand, int cs) {
    __shared__ u16 lds[2 * 8192];   // [buf][A 4096 | B 4096] shorts = 32 KB

    const int tid   = threadIdx.x;
    const int lane  = tid & 63;
    const int w     = tid >> 6;
    const int wr    = w >> 1, wc = w & 1;
    const int m0    = blockIdx.x * 128;
    const int cbase = blockIdx.y * GCH;

    // staging source permutation (LDS linear; stored slot8 = global_slot8 ^ line)
    const int s8g    = (lane & 7) ^ (lane >> 3);
    const int rowadd = 2 * (lane >> 3) + (s8g >> 2);
    const int koff   = (s8g & 3) * 8;

    const int fr = lane & 15;
    const int fq = lane >> 4;
    const int s8s = ((fr & 1) * 4 + fq) ^ (fr >> 1);  // swizzled read slot

    float ivx[16];
    #pragma unroll
    for (int i = 0; i < 4; ++i)
        #pragma unroll
        for (int r = 0; r < 4; ++r)
            ivx[i * 4 + r] = invx[m0 + wr * 64 + i * 16 + fq * 4 + r];

    float running[16];
    #pragma unroll
    for (int i = 0; i < 16; ++i) running[i] = -3.0e38f;

    f32x4 acc[4][4];
    #pragma unroll
    for (int i = 0; i < 4; ++i)
        #pragma unroll
        for (int j = 0; j < 4; ++j) acc[i][j] = (f32x4){0.f, 0.f, 0.f, 0.f};

    auto stage = [&](int buf, int gt, int k0) {
        #pragma unroll
        for (int q = 0; q < 2; ++q) {
            int R0 = w * 32 + q * 16;    // 16-row chunk = 8 swizzle lines
            async_copy16(xb + (size_t)(m0 + R0 + rowadd) * DD + k0 + koff,
                         &lds[buf * 8192 + R0 * 32]);
            async_copy16(gb + (size_t)(cbase + gt * 128 + R0 + rowadd) * DD + k0 + koff,
                         &lds[buf * 8192 + 4096 + R0 * 32]);
        }
    };

    stage(0, 0, 0);
    __syncthreads();

    int cur = 0;
    for (int s = 0; s < NSTEP; ++s) {
        const int gt = s >> 3;
        if (s < NSTEP - 1) stage(cur ^ 1, (s + 1) >> 3, ((s + 1) & 7) * 32);

        bf16x8 af[4], bf[4];
        #pragma unroll
        for (int i = 0; i < 4; ++i) {
            int lineA = wr * 32 + i * 8 + (fr >> 1);
            af[i] = *(const bf16x8*)&lds[cur * 8192 + lineA * 64 + s8s * 8];
            int lineB = wc * 32 + i * 8 + (fr >> 1);
            bf[i] = *(const bf16x8*)&lds[cur * 8192 + 4096 + lineB * 64 + s8s * 8];
        }
        #pragma unroll
        for (int i = 0; i < 4; ++i)
            #pragma unroll
            for (int j = 0; j < 4; ++j)
                acc[i][j] = __builtin_amdgcn_mfma_f32_16x16x32_bf16(
                    af[i], bf[j], acc[i][j], 0, 0, 0);

        if ((s & 7) == 7) {
            // ---- per-g-tile epilogue: monotone filter + candidate collect ----
            const int g0 = cbase + gt * 128;
            float ivg4[4];
            #pragma unroll
            for (int j = 0; j < 4; ++j) ivg4[j] = invg[g0 + wc * 64 + j * 16 + fr];
            #pragma unroll
            for (int i = 0; i < 4; ++i) {
                #pragma unroll
                for (int r = 0; r < 4; ++r) {
                    float u0 = acc[i][0][r] * ivg4[0];
                    float u1 = acc[i][1][r] * ivg4[1];
                    float u2 = acc[i][2][r] * ivg4[2];
                    float u3 = acc[i][3][r] * ivg4[3];
                    float sm = fmaxf(fmaxf(u0, u1), fmaxf(u2, u3));
                    #pragma unroll
                    for (int off = 1; off < 16; off <<= 1)
                        sm = fmaxf(sm, __shfl_xor(sm, off));   // strip max over fr
                    const int row = m0 + wr * 64 + i * 16 + fq * 4 + r;
                    const float ivxr = ivx[i * 4 + r];
                    float mcos = fmaxf(running[i * 4 + r], sm * ivxr);
                    u32 old = 0;
                    if (fr == 0) old = atomicMax(&amax[row], enc_f32(mcos));
                    old = __shfl(old, lane & 48);   // broadcast within fq group
                    float gmax = fmaxf(mcos, dec_f32(old));
                    running[i * 4 + r] = gmax;
                    float thr = gmax - EPS;
                    #pragma unroll
                    for (int j = 0; j < 4; ++j) {
                        float v = (j == 0 ? u0 : j == 1 ? u1 : j == 2 ? u2 : u3) * ivxr;
                        if (v >= thr) {
                            u32 c = atomicAdd(&ccnt[row], 1u);
                            if (c < (u32)cs) {
                                float vq = fminf(fmaxf((v + 1.0f) * 32768.0f, 0.0f),
                                                 65535.0f);
                                cand[(size_t)row * cs + c] =
                                    ((u32)vq << 16) |
                                    (u32)(g0 + wc * 64 + j * 16 + fr);
                            }
                        }
                    }
                }
            }
            #pragma unroll
            for (int i = 0; i < 4; ++i)
                #pragma unroll
                for (int j = 0; j < 4; ++j) acc[i][j] = (f32x4){0.f, 0.f, 0.f, 0.f};
        }
        __syncthreads();
        cur ^= 1;
    }
}

// ---------------- resolve: filter by final max, exact eval survivors ----------
__global__ __launch_bounds__(256)
void resolve_kernel(const float* __restrict__ x, const float* __restrict__ gf,
                    const float* __restrict__ invg, const u32* __restrict__ amax,
                    const u32* __restrict__ ccnt, const u32* __restrict__ cand,
                    int cs, float* __restrict__ sums, float* __restrict__ counts) {
    __shared__ float xs[4][DD];
    int wid = threadIdx.x >> 6, lane = threadIdx.x & 63;
    int row = blockIdx.x * 4 + wid;
    float4 xv = ((const float4*)(x + (size_t)row * DD))[lane];
    ((float4*)xs[wid])[lane] = xv;   // wave-local staging (same-wave consume)

    u32 cnt = ccnt[row];
    float best = -3.0e38f; int bcol = GG - 1;

    bool fast = (cnt >= 1 && cnt <= (u32)cs);
    u32 e = 0; u64 mask = 0;
    if (fast) {
        float thr = dec_f32(amax[row]) - EPS_R;    // final approx max - margin
        e = (lane < (int)cnt) ? cand[(size_t)row * cs + lane] : 0u;
        float qv = (float)(e >> 16) * (1.0f / 32768.0f) - 1.0f;
        mask = __ballot((lane < (int)cnt) && (qv >= thr));
        if (mask == 0) fast = false;               // paranoia: never empty
    }

    if (fast) {
        while (mask) {
            int c = (int)(__ffsll((unsigned long long)mask) - 1);
            mask &= mask - 1;
            int col = __shfl((int)(e & 0xffffu), c);
            float4 gv = ((const float4*)(gf + (size_t)col * DD))[lane];
            float p = fmaf(xv.x, gv.x, fmaf(xv.y, gv.y,
                      fmaf(xv.z, gv.z, xv.w * gv.w)));
            #pragma unroll
            for (int off = 1; off < 64; off <<= 1) p += __shfl_xor(p, off);
            float v = p * invg[col];
            if (v > best || (v == best && col < bcol)) { best = v; bcol = col; }
        }
    } else {
        // overflow fallback: exact scan over all groups
        for (int col = lane; col < GG; col += 64) {
            const float4* gr = (const float4*)(gf + (size_t)col * DD);
            float s = 0.f;
            #pragma unroll 8
            for (int d = 0; d < 64; ++d) {
                float4 g4 = gr[d];
                s = fmaf(xs[wid][d * 4 + 0], g4.x, s);
                s = fmaf(xs[wid][d * 4 + 1], g4.y, s);
                s = fmaf(xs[wid][d * 4 + 2], g4.z, s);
                s = fmaf(xs[wid][d * 4 + 3], g4.w, s);
            }
            float v = s * invg[col];
            if (v > best || (v == best && col < bcol)) { best = v; bcol = col; }
        }
        #pragma unroll
        for (int off = 1; off < 64; off <<= 1) {
            float ov = __shfl_xor(best, off);
            int   oc = __shfl_xor(bcol, off);
            if (ov > best || (ov == best && oc < bcol)) { best = ov; bcol = oc; }
        }
    }
    // fused scatter-mean accumulation
    if (lane == 0) atomicAdd(&counts[bcol], 1.0f);
    float* sp = sums + (size_t)bcol * DD + lane * 4;
    atomicAdd(sp + 0, xv.x); atomicAdd(sp + 1, xv.y);
    atomicAdd(sp + 2, xv.z); atomicAdd(sp + 3, xv.w);
}

// ---------------- EMA finalize ----------------
__global__ __launch_bounds__(256)
void final_kernel(const float* __restrict__ gf, const float* __restrict__ sums,
                  const float* __restrict__ counts, float* __restrict__ out) {
    int i = blockIdx.x * 256 + threadIdx.x;
    int g = i >> 8;
    out[i] = 0.99f * gf[i] + 0.01f * (sums[i] / fmaxf(counts[g], 1.0f));
}

extern "C" void kernel_launch(void* const* d_in, const int* in_sizes, int n_in,
                              void* d_out, int out_size, void* d_ws, size_t ws_size,
                              hipStream_t stream) {
    const float* x  = (const float*)d_in[0];   // [16384, 256]
    const float* gf = (const float*)d_in[1];   // [8192, 256]
    float* out = (float*)d_out;

    char* ws = (char*)d_ws;
    u16*   xb     = (u16*)ws;                       // 8 MB (sums aliases later)
    u16*   gb     = (u16*)(ws + 8388608);           // 4 MB
    float* invx   = (float*)(ws + 12582912);        // 64 KB
    float* invg   = (float*)(ws + 12648448);        // 32 KB
    u32*   amax   = (u32*)  (ws + 12681216);        // 64 KB
    u32*   ccnt   = (u32*)  (ws + 12746752);        // 64 KB
    float* counts = (float*)(ws + 12812288);        // 32 KB
    u32*   cand   = (u32*)  (ws + 12845056);        // cs*64K bytes (dynamic)
    float* sums   = (float*)ws;                     // aliases xb (dead after gemm)

    // candidate slots per row, sized to the workspace we actually have
    size_t cand_off = 12845056;
    int cs = 4;
    if (ws_size > cand_off) {
        size_t slots = (ws_size - cand_off) / ((size_t)BB * 4);
        cs = (int)(slots > 64 ? 64 : slots);
        if (cs < 4) cs = 4;
    }

    // zero amax+ccnt+counts (contiguous 160 KB)
    hipMemsetAsync(amax, 0, 160 * 1024, stream);

    prep_kernel<<<BB / 4, 256, 0, stream>>>(x,  xb, invx);
    prep_kernel<<<GG / 4, 256, 0, stream>>>(gf, gb, invg);

    gemm_kernel<<<dim3(BB / 128, GSPLIT), 256, 0, stream>>>(
        xb, gb, invx, invg, amax, ccnt, cand, cs);

    hipMemsetAsync(sums, 0, 8388608, stream);       // xb dead; reuse as sums

    resolve_kernel<<<BB / 4, 256, 0, stream>>>(
        x, gf, invg, amax, ccnt, cand, cs, sums, counts);
    final_kernel<<<GG * DD / 256, 256, 0, stream>>>(gf, sums, counts, out);
}